// Round 1
// baseline (994.295 us; speedup 1.0000x reference)
//
#include <hip/hip_runtime.h>
#include <hip/hip_bf16.h>
#include <math.h>

// ---------------------------------------------------------------------------
// BasicTransformer block on MI355X, bf16-MFMA implementation.
// B=2 S=2048 H=2048 NH=32 HD=64 FFN=8192
// ---------------------------------------------------------------------------

typedef __attribute__((ext_vector_type(8))) short bf16x8;
typedef __attribute__((ext_vector_type(4))) float f32x4;

#define DEV __device__ __forceinline__

static constexpr int SEQ  = 2048;
static constexpr int HID  = 2048;
static constexpr int NHEAD = 32;
static constexpr int HDIM = 64;
static constexpr int NFFN = 8192;
static constexpr int NTOK = 2 * SEQ;       // 4096 rows
static constexpr int QKVW = 3 * HID;       // 6144

DEV ushort f2bf(float f) {                 // RNE f32 -> bf16
  unsigned u = __float_as_uint(f);
  return (ushort)((u + 0x7fffu + ((u >> 16) & 1u)) >> 16);
}

DEV void gload16(const void* g, void* l) { // async global->LDS, 16B/lane
  __builtin_amdgcn_global_load_lds(
      (const __attribute__((address_space(1))) unsigned int*)g,
      (__attribute__((address_space(3))) unsigned int*)l, 16, 0, 0);
}

// ---------------------------------------------------------------------------
// transpose + convert: in [R][C] f32  ->  out [C][R] bf16
// ---------------------------------------------------------------------------
__global__ __launch_bounds__(256) void tcvt_kernel(const float* __restrict__ in,
                                                   ushort* __restrict__ out,
                                                   int R, int C) {
  __shared__ ushort tile[64][72];          // +8 pad breaks bank conflicts
  const int tr = blockIdx.y * 64, tc = blockIdx.x * 64;
  const int t = threadIdx.x;
  const int rr = t >> 2, c4 = (t & 3) * 16;
  const float4* ip = (const float4*)(in + (size_t)(tr + rr) * C + tc + c4);
  float4 a0 = ip[0], a1 = ip[1], a2 = ip[2], a3 = ip[3];
  ushort* tp = &tile[rr][c4];
  tp[0]=f2bf(a0.x); tp[1]=f2bf(a0.y); tp[2]=f2bf(a0.z); tp[3]=f2bf(a0.w);
  tp[4]=f2bf(a1.x); tp[5]=f2bf(a1.y); tp[6]=f2bf(a1.z); tp[7]=f2bf(a1.w);
  tp[8]=f2bf(a2.x); tp[9]=f2bf(a2.y); tp[10]=f2bf(a2.z); tp[11]=f2bf(a2.w);
  tp[12]=f2bf(a3.x); tp[13]=f2bf(a3.y); tp[14]=f2bf(a3.z); tp[15]=f2bf(a3.w);
  __syncthreads();
  union { ushort u[8]; bf16x8 v; } p0, p1;
#pragma unroll
  for (int j = 0; j < 8; ++j) { p0.u[j] = tile[c4 + j][rr]; p1.u[j] = tile[c4 + 8 + j][rr]; }
  ushort* op = out + (size_t)(tc + rr) * R + tr + c4;
  *(bf16x8*)op = p0.v;
  *(bf16x8*)(op + 8) = p1.v;
}

// ---------------------------------------------------------------------------
// LayerNorm row kernel: x [rows][2048] f32 -> out bf16
// ---------------------------------------------------------------------------
__global__ __launch_bounds__(256) void ln_kernel(const float* __restrict__ x,
                                                 const float* __restrict__ g,
                                                 const float* __restrict__ bb,
                                                 ushort* __restrict__ out) {
  const int row = blockIdx.x, t = threadIdx.x;
  const float4* xv = (const float4*)(x + (size_t)row * HID);
  float4 a0 = xv[t * 2], a1 = xv[t * 2 + 1];
  float s  = a0.x + a0.y + a0.z + a0.w + a1.x + a1.y + a1.z + a1.w;
  float ss = a0.x*a0.x + a0.y*a0.y + a0.z*a0.z + a0.w*a0.w
           + a1.x*a1.x + a1.y*a1.y + a1.z*a1.z + a1.w*a1.w;
#pragma unroll
  for (int o = 32; o > 0; o >>= 1) { s += __shfl_down(s, o); ss += __shfl_down(ss, o); }
  __shared__ float red[8];
  const int w = t >> 6, l = t & 63;
  if (l == 0) { red[w] = s; red[4 + w] = ss; }
  __syncthreads();
  s  = red[0] + red[1] + red[2] + red[3];
  ss = red[4] + red[5] + red[6] + red[7];
  const float mu = s * (1.f / HID);
  const float rs = rsqrtf(ss * (1.f / HID) - mu * mu + 1e-5f);
  const float4* gv = (const float4*)g;
  const float4* bv = (const float4*)bb;
  float4 g0 = gv[t * 2], g1 = gv[t * 2 + 1], b0 = bv[t * 2], b1 = bv[t * 2 + 1];
  union { ushort u[8]; bf16x8 v; } p;
  p.u[0] = f2bf((a0.x - mu) * rs * g0.x + b0.x);
  p.u[1] = f2bf((a0.y - mu) * rs * g0.y + b0.y);
  p.u[2] = f2bf((a0.z - mu) * rs * g0.z + b0.z);
  p.u[3] = f2bf((a0.w - mu) * rs * g0.w + b0.w);
  p.u[4] = f2bf((a1.x - mu) * rs * g1.x + b1.x);
  p.u[5] = f2bf((a1.y - mu) * rs * g1.y + b1.y);
  p.u[6] = f2bf((a1.z - mu) * rs * g1.z + b1.z);
  p.u[7] = f2bf((a1.w - mu) * rs * g1.w + b1.w);
  *(bf16x8*)(out + (size_t)row * HID + t * 8) = p.v;
}

// ---------------------------------------------------------------------------
// GEMM: C[M,N] = A[M,K](bf16) * BT[N,K](bf16)^T, fused epilogues.
// EPI 0: +bias -> bf16 out     1: +bias +res -> f32 out     2: +bias, gelu -> bf16
// 128x128 tile, BK=64, 4 waves (2x2), 16x16x32 bf16 MFMA, global_load_lds x16B.
// ---------------------------------------------------------------------------
template <int EPI>
__global__ __launch_bounds__(256) void gemm_kernel(const ushort* __restrict__ A,
                                                   const ushort* __restrict__ BT,
                                                   const float* __restrict__ bias,
                                                   const float* __restrict__ res,
                                                   void* __restrict__ outv,
                                                   int M, int N, int K) {
  __shared__ ushort As[128 * 64];
  __shared__ ushort Bs[128 * 64];
  const int t = threadIdx.x, w = t >> 6, l = t & 63;
  const int bn = blockIdx.x, bm = blockIdx.y;
  const int wr = w >> 1, wc = w & 1;
  const int l16 = l & 15, lg = l >> 4;
  const f32x4 z4 = {0.f, 0.f, 0.f, 0.f};
  f32x4 acc[4][4];
#pragma unroll
  for (int i = 0; i < 4; ++i)
#pragma unroll
    for (int j = 0; j < 4; ++j) acc[i][j] = z4;

  const ushort* aG = A  + ((size_t)bm * 128 + w * 32 + (l >> 3)) * K + (l & 7) * 8;
  const ushort* bG = BT + ((size_t)bn * 128 + w * 32 + (l >> 3)) * K + (l & 7) * 8;
  ushort* aS = &As[w * 32 * 64 + l * 8];
  ushort* bS = &Bs[w * 32 * 64 + l * 8];

  for (int kt = 0; kt < K; kt += 64) {
#pragma unroll
    for (int i = 0; i < 4; ++i) {
      gload16(aG + (size_t)i * 8 * K + kt, aS + i * 8 * 64);
      gload16(bG + (size_t)i * 8 * K + kt, bS + i * 8 * 64);
    }
    __syncthreads();   // drains vmcnt before barrier -> staged data visible
#pragma unroll
    for (int kk = 0; kk < 2; ++kk) {
      const int ko = kk * 32 + lg * 8;
      bf16x8 af[4], bfv[4];
#pragma unroll
      for (int mi = 0; mi < 4; ++mi)
        af[mi] = *(const bf16x8*)&As[(wr * 64 + mi * 16 + l16) * 64 + ko];
#pragma unroll
      for (int ni = 0; ni < 4; ++ni)
        bfv[ni] = *(const bf16x8*)&Bs[(wc * 64 + ni * 16 + l16) * 64 + ko];
#pragma unroll
      for (int mi = 0; mi < 4; ++mi)
#pragma unroll
        for (int ni = 0; ni < 4; ++ni)
          acc[mi][ni] = __builtin_amdgcn_mfma_f32_16x16x32_bf16(af[mi], bfv[ni], acc[mi][ni], 0, 0, 0);
    }
    __syncthreads();
  }

  const int col0 = bn * 128 + wc * 64 + l16;
  const int row0 = bm * 128 + wr * 64 + lg * 4;
#pragma unroll
  for (int ni = 0; ni < 4; ++ni) {
    const int col = col0 + ni * 16;
    const float bvl = bias[col];
#pragma unroll
    for (int mi = 0; mi < 4; ++mi) {
#pragma unroll
      for (int r = 0; r < 4; ++r) {
        const int row = row0 + mi * 16 + r;
        const size_t off = (size_t)row * N + col;
        float v = acc[mi][ni][r] + bvl;
        if (EPI == 1) {
          ((float*)outv)[off] = v + res[off];
        } else if (EPI == 2) {
          const float u = 0.7978845608f * (v + 0.044715f * v * v * v);
          ((ushort*)outv)[off] = f2bf(v / (1.f + __expf(-2.f * u)));  // v*0.5*(1+tanh(u))
        } else {
          ((ushort*)outv)[off] = f2bf(v);
        }
      }
    }
  }
}

// ---------------------------------------------------------------------------
// Flash attention. Grid (S/64, B*NH). 4 waves, each owns 16 q rows.
// K tile XOR-swizzled (pre-swizzled global source, swizzled ds_read).
// V reg-staged transposed into padded LDS. P relayout through wave-private LDS.
// ---------------------------------------------------------------------------
__global__ __launch_bounds__(256) void attn_kernel(const ushort* __restrict__ qkv,
                                                   ushort* __restrict__ ctx) {
  __shared__ ushort Kt[64 * 64];     // [kv][kdim], XOR-swizzled layout
  __shared__ ushort Vt[64][72];      // [d][kv], padded
  __shared__ ushort Pt[4][16][72];   // per-wave P [q][kv], padded
  const int qt = blockIdx.x, bh = blockIdx.y;
  const int b = bh >> 5, h = bh & 31;
  const int t = threadIdx.x, w = t >> 6, l = t & 63;
  const int l16 = l & 15, lg = l >> 4;
  const size_t rowbase = (size_t)(b * SEQ) * QKVW;
  const int hq = h * 192;            // head column base inside qkv row

  bf16x8 qf[2];
  {
    const ushort* qp = qkv + rowbase + (size_t)(qt * 64 + w * 16 + l16) * QKVW + hq + lg * 8;
    qf[0] = *(const bf16x8*)qp;
    qf[1] = *(const bf16x8*)(qp + 32);
  }
  const f32x4 z4 = {0.f, 0.f, 0.f, 0.f};
  f32x4 oacc[4];
#pragma unroll
  for (int i = 0; i < 4; ++i) oacc[i] = z4;
  float mr[4], lr[4];
#pragma unroll
  for (int r = 0; r < 4; ++r) { mr[r] = -1e30f; lr[r] = 0.f; }

  for (int kv0 = 0; kv0 < SEQ; kv0 += 64) {
    __syncthreads();                 // prior tile fully consumed
    // --- stage K (swizzle the *source* address; LDS dest stays linear) ---
#pragma unroll
    for (int i = 0; i < 2; ++i) {
      const int o  = (w * 16 + i * 8) * 128 + l * 16;   // linear dest byte
      const int so = o ^ ((o >> 3) & 0x70);             // involution swz
      const int srow = so >> 7, scol = (so & 127) >> 1;
      gload16(qkv + rowbase + (size_t)(kv0 + srow) * QKVW + hq + 64 + scol,
              (char*)Kt + o);
    }
    // --- stage V transposed ---
    {
      const int vr = t >> 2, c0 = (t & 3) * 16;
      const ushort* gV = qkv + rowbase + (size_t)(kv0 + vr) * QKVW + hq + 128 + c0;
      union { ushort u[8]; bf16x8 v; } u0, u1;
      u0.v = *(const bf16x8*)gV;
      u1.v = *(const bf16x8*)(gV + 8);
#pragma unroll
      for (int j = 0; j < 8; ++j) { Vt[c0 + j][vr] = u0.u[j]; Vt[c0 + 8 + j][vr] = u1.u[j]; }
    }
    __syncthreads();

    // --- S = (Q K^T) * 1/8 ---
    f32x4 sv[4];
#pragma unroll
    for (int n = 0; n < 4; ++n) sv[n] = z4;
#pragma unroll
    for (int n = 0; n < 4; ++n)
#pragma unroll
      for (int kk = 0; kk < 2; ++kk) {
        const int p = (n * 16 + l16) * 128 + kk * 64 + lg * 16;
        const int sp = p ^ ((p >> 3) & 0x70);
        bf16x8 kf = *(const bf16x8*)((const char*)Kt + sp);
        sv[n] = __builtin_amdgcn_mfma_f32_16x16x32_bf16(qf[kk], kf, sv[n], 0, 0, 0);
      }
    // --- online softmax (rows live in lanes (lg*4+r) of each 16-lane group) ---
    float sc[4][4], vmax[4];
#pragma unroll
    for (int r = 0; r < 4; ++r) vmax[r] = -1e30f;
#pragma unroll
    for (int n = 0; n < 4; ++n)
#pragma unroll
      for (int r = 0; r < 4; ++r) {
        const float xv = sv[n][r] * 0.125f;
        sc[n][r] = xv; vmax[r] = fmaxf(vmax[r], xv);
      }
#pragma unroll
    for (int mask = 1; mask < 16; mask <<= 1)
#pragma unroll
      for (int r = 0; r < 4; ++r) vmax[r] = fmaxf(vmax[r], __shfl_xor(vmax[r], mask));
    float sf[4], rsum[4];
#pragma unroll
    for (int r = 0; r < 4; ++r) {
      const float mn = fmaxf(mr[r], vmax[r]);
      sf[r] = __expf(mr[r] - mn);
      mr[r] = mn; rsum[r] = 0.f;
    }
    ushort pb[4][4];
#pragma unroll
    for (int n = 0; n < 4; ++n)
#pragma unroll
      for (int r = 0; r < 4; ++r) {
        const float pv = __expf(sc[n][r] - mr[r]);
        rsum[r] += pv; pb[n][r] = f2bf(pv);
      }
#pragma unroll
    for (int mask = 1; mask < 16; mask <<= 1)
#pragma unroll
      for (int r = 0; r < 4; ++r) rsum[r] += __shfl_xor(rsum[r], mask);
#pragma unroll
    for (int r = 0; r < 4; ++r) lr[r] = lr[r] * sf[r] + rsum[r];
#pragma unroll
    for (int nd = 0; nd < 4; ++nd)
#pragma unroll
      for (int r = 0; r < 4; ++r) oacc[nd][r] *= sf[r];
    // --- P relayout via wave-private LDS ---
#pragma unroll
    for (int n = 0; n < 4; ++n)
#pragma unroll
      for (int r = 0; r < 4; ++r) Pt[w][lg * 4 + r][n * 16 + l16] = pb[n][r];
    asm volatile("s_waitcnt lgkmcnt(0)" ::: "memory");
    __builtin_amdgcn_sched_barrier(0);
    bf16x8 pa[2];
#pragma unroll
    for (int kk = 0; kk < 2; ++kk) pa[kk] = *(const bf16x8*)&Pt[w][l16][kk * 32 + lg * 8];
    // --- O += P V ---
#pragma unroll
    for (int nd = 0; nd < 4; ++nd)
#pragma unroll
      for (int kk = 0; kk < 2; ++kk) {
        bf16x8 vf = *(const bf16x8*)&Vt[nd * 16 + l16][kk * 32 + lg * 8];
        oacc[nd] = __builtin_amdgcn_mfma_f32_16x16x32_bf16(pa[kk], vf, oacc[nd], 0, 0, 0);
      }
  }
  // --- normalize + write ctx[b*S+q][h*64 + d] ---
#pragma unroll
  for (int r = 0; r < 4; ++r) {
    const float inv = 1.f / lr[r];
    const int row = qt * 64 + w * 16 + lg * 4 + r;
    const size_t base = (size_t)(b * SEQ + row) * HID + h * HDIM + l16;
#pragma unroll
    for (int nd = 0; nd < 4; ++nd) ctx[base + nd * 16] = f2bf(oacc[nd][r] * inv);
  }
}

// ---------------------------------------------------------------------------
extern "C" void kernel_launch(void* const* d_in, const int* in_sizes, int n_in,
                              void* d_out, int out_size, void* d_ws, size_t ws_size,
                              hipStream_t stream) {
  const float* x      = (const float*)d_in[0];
  const float* ln1g   = (const float*)d_in[1];
  const float* ln1b   = (const float*)d_in[2];
  const float* w_qkv  = (const float*)d_in[3];
  const float* b_qkv  = (const float*)d_in[4];
  const float* w_proj = (const float*)d_in[5];
  const float* b_proj = (const float*)d_in[6];
  const float* ln2g   = (const float*)d_in[7];
  const float* ln2b   = (const float*)d_in[8];
  const float* w1     = (const float*)d_in[9];
  const float* b1     = (const float*)d_in[10];
  const float* w2     = (const float*)d_in[11];
  const float* b2     = (const float*)d_in[12];

  char* ws = (char*)d_ws;
  // carve workspace (bytes). total = 224 MiB
  ushort* wqkvT = (ushort*)(ws + 0);            // [6144][2048] bf16  25165824
  ushort* wprojT = (ushort*)(ws + 25165824);    // [2048][2048] bf16   8388608
  ushort* w1T   = (ushort*)(ws + 33554432);     // [8192][2048] bf16  33554432
  ushort* w2T   = (ushort*)(ws + 67108864);     // [2048][8192] bf16  33554432
  ushort* hbuf  = (ushort*)(ws + 100663296);    // [4096][2048] bf16  16777216
  ushort* qkvb  = (ushort*)(ws + 117440512);    // [4096][6144] bf16 (reused as gelu [4096][8192]) 67108864
  ushort* ctxb  = (ushort*)(ws + 184549376);    // [4096][2048] bf16  16777216
  float*  x2    = (float*)(ws + 201326592);     // [4096][2048] f32   33554432

  // weights: transpose + convert to bf16 [N][K]
  tcvt_kernel<<<dim3(96, 32),  256, 0, stream>>>(w_qkv,  wqkvT, 2048, 6144);
  tcvt_kernel<<<dim3(32, 32),  256, 0, stream>>>(w_proj, wprojT, 2048, 2048);
  tcvt_kernel<<<dim3(128, 32), 256, 0, stream>>>(w1,     w1T,   2048, 8192);
  tcvt_kernel<<<dim3(32, 128), 256, 0, stream>>>(w2,     w2T,   8192, 2048);

  // LN1 -> h (bf16)
  ln_kernel<<<NTOK, 256, 0, stream>>>(x, ln1g, ln1b, hbuf);
  // QKV = h @ w_qkv + b_qkv  (bf16 out)
  gemm_kernel<0><<<dim3(48, 32), 256, 0, stream>>>(hbuf, wqkvT, b_qkv, nullptr, qkvb, NTOK, QKVW, HID);
  // attention -> ctx (bf16)
  attn_kernel<<<dim3(SEQ / 64, 2 * NHEAD), 256, 0, stream>>>(qkvb, ctxb);
  // x2 = ctx @ w_proj + b_proj + x   (f32)
  gemm_kernel<1><<<dim3(16, 32), 256, 0, stream>>>(ctxb, wprojT, b_proj, x, x2, NTOK, HID, HID);
  // LN2 -> h (bf16)
  ln_kernel<<<NTOK, 256, 0, stream>>>(x2, ln2g, ln2b, hbuf);
  // g = gelu(h @ w1 + b1)  (bf16)
  gemm_kernel<2><<<dim3(64, 32), 256, 0, stream>>>(hbuf, w1T, b1, nullptr, qkvb, NTOK, NFFN, HID);
  // out = g @ w2 + b2 + x2  (f32)
  gemm_kernel<1><<<dim3(16, 32), 256, 0, stream>>>(qkvb, w2T, b2, x2, (float*)d_out, NTOK, HID, NFFN);
}